// Round 4
// baseline (1643.065 us; speedup 1.0000x reference)
//
#include <hip/hip_runtime.h>
#include <hip/hip_bf16.h>

#define NB 2
#define NQ 20000
#define DM 64
#define NH 8
#define NL 5
#define NP 4
#define LIN 45109
#define FFN 1024

__device__ __forceinline__ float lo16(unsigned u) { return __uint_as_float(u << 16); }
__device__ __forceinline__ float hi16(unsigned u) { return __uint_as_float(u & 0xffff0000u); }

template <bool BF16>
__device__ __forceinline__ float ldT(const void* p, size_t i) {
    if constexpr (BF16) return __bfloat162float(((const __hip_bfloat16*)p)[i]);
    else return ((const float*)p)[i];
}

// g1 is all-ones in every dtype: bf16 pair = 0x3F803F80, f32 = 0x3F800000.
__device__ __forceinline__ bool detect_bf16(const void* g1) {
    return *((const unsigned*)g1) == 0x3F803F80u;
}

// ---- kernel 1: val[row,c] = (dvf_b[row,:] @ Wv + bv)[c], one batch, bf16 out ----
template <bool BF16>
__global__ void val_proj_kernel(const void* __restrict__ dvf_b,
                                const void* __restrict__ Wv,
                                const void* __restrict__ bv,
                                const void* __restrict__ g1,
                                __hip_bfloat16* __restrict__ val) {
    if (detect_bf16(g1) != BF16) return;
    const int lane = threadIdx.x & 63;
    const int row = blockIdx.x * 4 + (threadIdx.x >> 6);
    if (row >= LIN) return;
    float mine = ldT<BF16>(dvf_b, (size_t)row * DM + lane);
    float acc = ldT<BF16>(bv, lane);
#pragma unroll 8
    for (int k = 0; k < DM; k++) {
        float vk = __shfl(mine, k, 64);
        acc = fmaf(vk, ldT<BF16>(Wv, k * DM + lane), acc);
    }
    val[(size_t)row * DM + lane] = __float2bfloat16(acc);
}

// ---- kernel 2: W2T[c*1024+u] = W2[u*64+c] (bf16 out) ----
template <bool BF16>
__global__ void w2_transpose_kernel(const void* __restrict__ W2,
                                    const void* __restrict__ g1,
                                    __hip_bfloat16* __restrict__ W2T) {
    if (detect_bf16(g1) != BF16) return;
    int idx = blockIdx.x * 256 + threadIdx.x;   // 65536 total
    int u = idx >> 6, c = idx & 63;
    W2T[c * FFN + u] = __float2bfloat16(ldT<BF16>(W2, idx));
}

// ---- kernel 3: fused per-query (one batch; pointers pre-offset on host) ----
template <bool BF16>
__global__ void __launch_bounds__(256)
fused_kernel(const void* __restrict__ q_feat,
             const void* __restrict__ ref_pts,
             const void* __restrict__ q_pos,
             const void* __restrict__ Wo, const void* __restrict__ bo,
             const void* __restrict__ Wa, const void* __restrict__ ba,
             const void* __restrict__ Wout, const void* __restrict__ bout,
             const void* __restrict__ g1, const void* __restrict__ b1,
             const void* __restrict__ W1, const void* __restrict__ bff1,
             const __hip_bfloat16* __restrict__ W2T, const void* __restrict__ bff2,
             const void* __restrict__ g2, const void* __restrict__ b2,
             const __hip_bfloat16* __restrict__ val,
             void* __restrict__ out) {
    if (detect_bf16(g1) != BF16) return;

    __shared__ __align__(16) float qs[4][DM];
    __shared__ __align__(16) float offs[4][NH * NL * NP * 2];   // 320
    __shared__ __align__(16) float aws[4][NH * NL * NP];        // 160
    __shared__ __align__(16) float outv[4][DM];
    __shared__ __align__(16) float xs[4][DM];
    __shared__ __align__(16) float hid[4][FFN];

    const int lane = threadIdx.x & 63;
    const int w = threadIdx.x >> 6;
    const int qi = blockIdx.x * 4 + w;          // grid = 5000 -> qi < 20000

    const int sz[NL]  = {184, 92, 46, 23, 12};
    const int lsi[NL] = {0, 33856, 42320, 44436, 44965};

    // ---- phase A: q = q_feat + q_pos ----
    const float qf = ldT<BF16>(q_feat, (size_t)qi * DM + lane);
    const float qp = ldT<BF16>(q_pos, (size_t)qi * DM + lane);
    qs[w][lane] = qf + qp;
    const float refx = ldT<BF16>(ref_pts, (size_t)qi * 2 + 0);
    const float refy = ldT<BF16>(ref_pts, (size_t)qi * 2 + 1);
    __syncthreads();

    // ---- phase B: offsets (320) and attn logits (160) ----
    {
        float acco[5] = {0.f, 0.f, 0.f, 0.f, 0.f};
        float acca[3] = {0.f, 0.f, 0.f};
#pragma unroll 4
        for (int k = 0; k < DM; k++) {
            const float qk = qs[w][k];
#pragma unroll
            for (int j = 0; j < 5; j++)
                acco[j] = fmaf(qk, ldT<BF16>(Wo, (size_t)k * 320 + lane + 64 * j), acco[j]);
            acca[0] = fmaf(qk, ldT<BF16>(Wa, (size_t)k * 160 + lane), acca[0]);
            acca[1] = fmaf(qk, ldT<BF16>(Wa, (size_t)k * 160 + lane + 64), acca[1]);
            if (lane < 32) acca[2] = fmaf(qk, ldT<BF16>(Wa, (size_t)k * 160 + lane + 128), acca[2]);
        }
#pragma unroll
        for (int j = 0; j < 5; j++)
            offs[w][lane + 64 * j] = acco[j] + ldT<BF16>(bo, lane + 64 * j);
        aws[w][lane]      = acca[0] + ldT<BF16>(ba, lane);
        aws[w][lane + 64] = acca[1] + ldT<BF16>(ba, lane + 64);
        if (lane < 32) aws[w][lane + 128] = acca[2] + ldT<BF16>(ba, lane + 128);
    }
    __syncthreads();

    // ---- softmax per head over 20 (lanes 0..7) ----
    if (lane < NH) {
        float* p = &aws[w][lane * (NL * NP)];
        float m = p[0];
        for (int j = 1; j < NL * NP; j++) m = fmaxf(m, p[j]);
        float s = 0.f;
        for (int j = 0; j < NL * NP; j++) { float e = expf(p[j] - m); p[j] = e; s += e; }
        float inv = 1.f / s;
        for (int j = 0; j < NL * NP; j++) p[j] *= inv;
    }
    __syncthreads();

    // ---- phase C: bilinear sampling; lane = h*8 + d ----
    {
        const int h = lane >> 3;
        const __hip_bfloat16* vbase = val + lane;
        float acc = 0.f;
#pragma unroll
        for (int l = 0; l < NL; l++) {
            const int Wl = sz[l];
            const float Wf = (float)Wl;
            const int st = lsi[l];
#pragma unroll
            for (int p = 0; p < NP; p++) {
                const int c = ((h * NL + l) * NP + p) * 2;
                const float ox = offs[w][c], oy = offs[w][c + 1];
                const float lx = refx + ox / Wf;
                const float ly = refy + oy / Wf;     // square levels: H == W
                const float fx = lx * Wf - 0.5f;
                const float fy = ly * Wf - 0.5f;
                const float x0f = floorf(fx), y0f = floorf(fy);
                const float wx = fx - x0f, wy = fy - y0f;
                const int x0 = (int)x0f, y0 = (int)y0f;
                const float aV = aws[w][h * (NL * NP) + l * NP + p];
                float s = 0.f;
                if (x0 >= 0 && x0 < Wl && y0 >= 0 && y0 < Wl)
                    s = fmaf(__bfloat162float(vbase[(size_t)(st + y0 * Wl + x0) * DM]), (1.f - wx) * (1.f - wy), s);
                if (x0 + 1 >= 0 && x0 + 1 < Wl && y0 >= 0 && y0 < Wl)
                    s = fmaf(__bfloat162float(vbase[(size_t)(st + y0 * Wl + x0 + 1) * DM]), wx * (1.f - wy), s);
                if (x0 >= 0 && x0 < Wl && y0 + 1 >= 0 && y0 + 1 < Wl)
                    s = fmaf(__bfloat162float(vbase[(size_t)(st + (y0 + 1) * Wl + x0) * DM]), (1.f - wx) * wy, s);
                if (x0 + 1 >= 0 && x0 + 1 < Wl && y0 + 1 >= 0 && y0 + 1 < Wl)
                    s = fmaf(__bfloat162float(vbase[(size_t)(st + (y0 + 1) * Wl + x0 + 1) * DM]), wx * wy, s);
                acc = fmaf(aV, s, acc);
            }
        }
        outv[w][lane] = acc;
    }
    __syncthreads();

    // ---- phase D: attn_out @ Wout + bout; residual; LN1 ----
    float x1;
    {
        float attn = ldT<BF16>(bout, lane);
#pragma unroll 8
        for (int k = 0; k < DM; k++)
            attn = fmaf(outv[w][k], ldT<BF16>(Wout, (size_t)k * DM + lane), attn);
        const float xpre = qf + attn;
        float s = xpre, s2 = xpre * xpre;
#pragma unroll
        for (int o = 32; o >= 1; o >>= 1) {
            s += __shfl_xor(s, o, 64);
            s2 += __shfl_xor(s2, o, 64);
        }
        const float mean = s * (1.f / 64.f);
        const float var = s2 * (1.f / 64.f) - mean * mean;
        const float xn = (xpre - mean) * rsqrtf(var + 1e-5f);
        x1 = xn * ldT<BF16>(g1, lane) + ldT<BF16>(b1, lane);
        xs[w][lane] = x1;
    }
    __syncthreads();

    // ---- phase E1: hidden = relu(x @ W1 + bff1); lane owns [lane*16, lane*16+16) ----
    {
        const int u0 = lane * 16;
        float acc[16];
#pragma unroll
        for (int j = 0; j < 16; j++) acc[j] = ldT<BF16>(bff1, u0 + j);
        for (int k = 0; k < DM; k++) {
            const float xk = xs[w][k];
            const size_t base = (size_t)k * FFN + u0;
#pragma unroll
            for (int j = 0; j < 16; j++)
                acc[j] = fmaf(ldT<BF16>(W1, base + j), xk, acc[j]);
        }
        float4* hp = reinterpret_cast<float4*>(&hid[w][u0]);
#pragma unroll
        for (int j = 0; j < 4; j++) {
            float4 v;
            v.x = fmaxf(acc[4 * j + 0], 0.f);
            v.y = fmaxf(acc[4 * j + 1], 0.f);
            v.z = fmaxf(acc[4 * j + 2], 0.f);
            v.w = fmaxf(acc[4 * j + 3], 0.f);
            hp[j] = v;
        }
    }
    __syncthreads();

    // ---- phase E2: y = hidden @ W2 + bff2 (W2T bf16 row is contiguous) ----
    {
        float y = ldT<BF16>(bff2, lane);
        const uint4* wr = reinterpret_cast<const uint4*>(W2T + (size_t)lane * FFN);
        const float4* hv = reinterpret_cast<const float4*>(&hid[w][0]);
#pragma unroll 4
        for (int t = 0; t < FFN / 8; t++) {
            const uint4 A = wr[t];
            const float4 h0 = hv[2 * t];
            const float4 h1 = hv[2 * t + 1];
            y = fmaf(lo16(A.x), h0.x, y);
            y = fmaf(hi16(A.x), h0.y, y);
            y = fmaf(lo16(A.y), h0.z, y);
            y = fmaf(hi16(A.y), h0.w, y);
            y = fmaf(lo16(A.z), h1.x, y);
            y = fmaf(hi16(A.z), h1.y, y);
            y = fmaf(lo16(A.w), h1.z, y);
            y = fmaf(hi16(A.w), h1.w, y);
        }
        const float xpre = x1 + y;
        float s = xpre, s2 = xpre * xpre;
#pragma unroll
        for (int o = 32; o >= 1; o >>= 1) {
            s += __shfl_xor(s, o, 64);
            s2 += __shfl_xor(s2, o, 64);
        }
        const float mean = s * (1.f / 64.f);
        const float var = s2 * (1.f / 64.f) - mean * mean;
        const float xn = (xpre - mean) * rsqrtf(var + 1e-5f);
        const float res = xn * ldT<BF16>(g2, lane) + ldT<BF16>(b2, lane);
        if constexpr (BF16)
            ((__hip_bfloat16*)out)[(size_t)qi * DM + lane] = __float2bfloat16(res);
        else
            ((float*)out)[(size_t)qi * DM + lane] = res;
    }
}

extern "C" void kernel_launch(void* const* d_in, const int* in_sizes, int n_in,
                              void* d_out, int out_size, void* d_ws, size_t ws_size,
                              hipStream_t stream) {
    // Weight base auto-detect: spatial_shapes (10 ints) + level_start_index (5)
    // present -> weights start at 6; omitted -> Wv (4096 elems) sits at index 4.
    const int B0 = (in_sizes[4] >= 4096) ? 4 : 6;
    const void* q_feat = d_in[0];
    const void* dvf    = d_in[1];
    const void* refp   = d_in[2];
    const void* q_pos  = d_in[3];
    const void* Wv   = d_in[B0 + 0];
    const void* bv   = d_in[B0 + 1];
    const void* Wo   = d_in[B0 + 2];
    const void* bo   = d_in[B0 + 3];
    const void* Wa   = d_in[B0 + 4];
    const void* ba   = d_in[B0 + 5];
    const void* Wout = d_in[B0 + 6];
    const void* bout = d_in[B0 + 7];
    const void* g1   = d_in[B0 + 8];
    const void* b1   = d_in[B0 + 9];
    const void* W1   = d_in[B0 + 10];
    const void* bff1 = d_in[B0 + 11];
    const void* W2   = d_in[B0 + 12];
    const void* bff2 = d_in[B0 + 13];
    const void* g2   = d_in[B0 + 14];
    const void* b2   = d_in[B0 + 15];

    // element strides for batch offsets depend on dtype only through pointer
    // arithmetic; do it in bytes with a runtime-unknown dtype by offsetting in
    // elements for BOTH variants (each variant interprets its own pointer).
    // bf16 variant: elem = 2B; f32 variant: elem = 4B. We pass base pointers
    // and let the kernel index by element; per-batch offset must match dtype,
    // so compute both offsets and pass the right pointer per instantiation.

    __hip_bfloat16* val = (__hip_bfloat16*)d_ws;                 // 5.77 MB
    __hip_bfloat16* W2T = (__hip_bfloat16*)d_ws + (size_t)LIN * DM;  // +128 KB

    w2_transpose_kernel<true ><<<(DM * FFN) / 256, 256, 0, stream>>>(W2, g1, W2T);
    w2_transpose_kernel<false><<<(DM * FFN) / 256, 256, 0, stream>>>(W2, g1, W2T);

    for (int b = 0; b < NB; b++) {
        const size_t vo = (size_t)b * LIN * DM;   // elements
        const size_t qo = (size_t)b * NQ * DM;
        const size_t ro = (size_t)b * NQ * 2;
        // bf16 variant
        val_proj_kernel<true><<<(LIN + 3) / 4, 256, 0, stream>>>(
            (const void*)((const __hip_bfloat16*)dvf + vo), Wv, bv, g1, val);
        fused_kernel<true><<<NQ / 4, 256, 0, stream>>>(
            (const void*)((const __hip_bfloat16*)q_feat + qo),
            (const void*)((const __hip_bfloat16*)refp + ro),
            (const void*)((const __hip_bfloat16*)q_pos + qo),
            Wo, bo, Wa, ba, Wout, bout, g1, b1, W1, bff1, W2T, bff2, g2, b2,
            val, (void*)((__hip_bfloat16*)d_out + qo));
        // f32 variant
        val_proj_kernel<false><<<(LIN + 3) / 4, 256, 0, stream>>>(
            (const void*)((const float*)dvf + vo), Wv, bv, g1, val);
        fused_kernel<false><<<NQ / 4, 256, 0, stream>>>(
            (const void*)((const float*)q_feat + qo),
            (const void*)((const float*)refp + ro),
            (const void*)((const float*)q_pos + qo),
            Wo, bo, Wa, ba, Wout, bout, g1, b1, W1, bff1, W2T, bff2, g2, b2,
            val, (void*)((float*)d_out + qo));
    }
}

// Round 5
// 667.247 us; speedup vs baseline: 2.4625x; 2.4625x over previous
//
#include <hip/hip_runtime.h>
#include <hip/hip_bf16.h>

#define NB 2
#define NQ 20000
#define DM 64
#define NH 8
#define NL 5
#define NP 4
#define LIN 45109
#define FFN 1024

// ---- kernel 1: val[row,c] = (dvf_b[row,:] @ Wv + bv)[c], one batch, bf16 out ----
__global__ void val_proj_kernel(const float* __restrict__ dvf_b,
                                const float* __restrict__ Wv,
                                const float* __restrict__ bv,
                                __hip_bfloat16* __restrict__ val) {
    const int lane = threadIdx.x & 63;
    const int row = blockIdx.x * 4 + (threadIdx.x >> 6);
    if (row >= LIN) return;
    float mine = dvf_b[(size_t)row * DM + lane];
    float acc = bv[lane];
#pragma unroll 8
    for (int k = 0; k < DM; k++) {
        float vk = __shfl(mine, k, 64);
        acc = fmaf(vk, Wv[k * DM + lane], acc);
    }
    val[(size_t)row * DM + lane] = __float2bfloat16(acc);
}

// ---- kernel 2: fused per-query block (4 queries / 256 threads), f32 in/out ----
__global__ void __launch_bounds__(256)
fused_kernel(const float* __restrict__ q_feat,
             const float* __restrict__ ref_pts,
             const float* __restrict__ q_pos,
             const float* __restrict__ Wo, const float* __restrict__ bo,
             const float* __restrict__ Wa, const float* __restrict__ ba,
             const float* __restrict__ Wout, const float* __restrict__ bout,
             const float* __restrict__ g1, const float* __restrict__ b1,
             const float* __restrict__ W1, const float* __restrict__ bff1,
             const float* __restrict__ W2, const float* __restrict__ bff2,
             const float* __restrict__ g2, const float* __restrict__ b2,
             const __hip_bfloat16* __restrict__ val,
             float* __restrict__ out) {
    __shared__ __align__(16) float qs[4][DM];
    __shared__ __align__(16) float offs[4][NH * NL * NP * 2];   // 320
    __shared__ __align__(16) float aws[4][NH * NL * NP];        // 160
    __shared__ __align__(16) float outv[4][DM];
    __shared__ __align__(16) float xs[4][DM];
    __shared__ __align__(16) float hid[4][FFN];
    __shared__ __align__(16) float red[4][4][DM];

    const int tid = threadIdx.x;
    const int lane = tid & 63;
    const int w = tid >> 6;
    const int qi = blockIdx.x * 4 + w;          // grid = 5000 -> qi < 20000

    const int sz[NL]  = {184, 92, 46, 23, 12};
    const int lsi[NL] = {0, 33856, 42320, 44436, 44965};

    // ---- phase A: q = q_feat + q_pos (per wave) ----
    const float qf = q_feat[(size_t)qi * DM + lane];
    const float qp = q_pos[(size_t)qi * DM + lane];
    qs[w][lane] = qf + qp;
    const float refx = ref_pts[(size_t)qi * 2 + 0];
    const float refy = ref_pts[(size_t)qi * 2 + 1];
    __syncthreads();

    // ---- phase B (cooperative): 480 output cols (320 Wo + 160 Wa), 2 per thread ----
    {
        // col0 = tid (always Wo since 256 < 320); col1 = tid + 256
        const int v1 = tid + 256;
        const float* base1;
        int stride1;
        bool act1 = true;
        bool is_off1 = true;
        if (v1 < 320) { base1 = Wo + v1; stride1 = 320; }
        else if (v1 < 480) { base1 = Wa + (v1 - 320); stride1 = 160; is_off1 = false; }
        else { base1 = Wo + tid; stride1 = 320; act1 = false; }

        float a0[4] = {0.f, 0.f, 0.f, 0.f};
        float a1[4] = {0.f, 0.f, 0.f, 0.f};
        for (int k4 = 0; k4 < DM; k4 += 4) {
            const float4 q0 = *(const float4*)&qs[0][k4];
            const float4 q1 = *(const float4*)&qs[1][k4];
            const float4 q2 = *(const float4*)&qs[2][k4];
            const float4 q3 = *(const float4*)&qs[3][k4];
#pragma unroll
            for (int dk = 0; dk < 4; dk++) {
                const int k = k4 + dk;
                const float w0 = Wo[k * 320 + tid];
                const float w1 = base1[k * stride1];
                const float e0 = (&q0.x)[dk], e1 = (&q1.x)[dk];
                const float e2 = (&q2.x)[dk], e3 = (&q3.x)[dk];
                a0[0] = fmaf(e0, w0, a0[0]); a1[0] = fmaf(e0, w1, a1[0]);
                a0[1] = fmaf(e1, w0, a0[1]); a1[1] = fmaf(e1, w1, a1[1]);
                a0[2] = fmaf(e2, w0, a0[2]); a1[2] = fmaf(e2, w1, a1[2]);
                a0[3] = fmaf(e3, w0, a0[3]); a1[3] = fmaf(e3, w1, a1[3]);
            }
        }
        const float bo0 = bo[tid];
#pragma unroll
        for (int q = 0; q < 4; q++) offs[q][tid] = a0[q] + bo0;
        if (act1) {
            if (is_off1) {
                const float bb = bo[v1];
#pragma unroll
                for (int q = 0; q < 4; q++) offs[q][v1] = a1[q] + bb;
            } else {
                const float bb = ba[v1 - 320];
#pragma unroll
                for (int q = 0; q < 4; q++) aws[q][v1 - 320] = a1[q] + bb;
            }
        }
    }
    __syncthreads();

    // ---- softmax per head over 20 (wave w handles query w, lanes 0..7) ----
    if (lane < NH) {
        float* p = &aws[w][lane * (NL * NP)];
        float m = p[0];
        for (int j = 1; j < NL * NP; j++) m = fmaxf(m, p[j]);
        float s = 0.f;
        for (int j = 0; j < NL * NP; j++) { float e = expf(p[j] - m); p[j] = e; s += e; }
        float inv = 1.f / s;
        for (int j = 0; j < NL * NP; j++) p[j] *= inv;
    }
    __syncthreads();

    // ---- phase C: bilinear sampling (per wave); lane = h*8 + d ----
    {
        const int h = lane >> 3;
        const __hip_bfloat16* vbase = val + lane;
        float acc = 0.f;
#pragma unroll
        for (int l = 0; l < NL; l++) {
            const int Wl = sz[l];
            const float Wf = (float)Wl;
            const int st = lsi[l];
#pragma unroll
            for (int p = 0; p < NP; p++) {
                const int c = ((h * NL + l) * NP + p) * 2;
                const float ox = offs[w][c], oy = offs[w][c + 1];
                const float fx = (refx + ox / Wf) * Wf - 0.5f;
                const float fy = (refy + oy / Wf) * Wf - 0.5f;   // square levels
                const float x0f = floorf(fx), y0f = floorf(fy);
                const float wx = fx - x0f, wy = fy - y0f;
                const int x0 = (int)x0f, y0 = (int)y0f;
                const float aV = aws[w][h * (NL * NP) + l * NP + p];
                float s = 0.f;
                if (x0 >= 0 && x0 < Wl && y0 >= 0 && y0 < Wl)
                    s = fmaf(__bfloat162float(vbase[(size_t)(st + y0 * Wl + x0) * DM]), (1.f - wx) * (1.f - wy), s);
                if (x0 + 1 >= 0 && x0 + 1 < Wl && y0 >= 0 && y0 < Wl)
                    s = fmaf(__bfloat162float(vbase[(size_t)(st + y0 * Wl + x0 + 1) * DM]), wx * (1.f - wy), s);
                if (x0 >= 0 && x0 < Wl && y0 + 1 >= 0 && y0 + 1 < Wl)
                    s = fmaf(__bfloat162float(vbase[(size_t)(st + (y0 + 1) * Wl + x0) * DM]), (1.f - wx) * wy, s);
                if (x0 + 1 >= 0 && x0 + 1 < Wl && y0 + 1 >= 0 && y0 + 1 < Wl)
                    s = fmaf(__bfloat162float(vbase[(size_t)(st + (y0 + 1) * Wl + x0 + 1) * DM]), wx * wy, s);
                acc = fmaf(aV, s, acc);
            }
        }
        outv[w][lane] = acc;
    }
    __syncthreads();

    // ---- phase D: attn_out @ Wout + bout; residual; LN1 (per wave) ----
    {
        float attn = bout[lane];
#pragma unroll 8
        for (int k = 0; k < DM; k++)
            attn = fmaf(outv[w][k], Wout[k * DM + lane], attn);
        const float xpre = qf + attn;
        float s = xpre, s2 = xpre * xpre;
#pragma unroll
        for (int o = 32; o >= 1; o >>= 1) {
            s += __shfl_xor(s, o, 64);
            s2 += __shfl_xor(s2, o, 64);
        }
        const float mean = s * (1.f / 64.f);
        const float var = s2 * (1.f / 64.f) - mean * mean;
        const float xn = (xpre - mean) * rsqrtf(var + 1e-5f);
        xs[w][lane] = xn * g1[lane] + b1[lane];
    }
    __syncthreads();

    // ---- phase E1 (cooperative): hidden = relu(x @ W1 + bff1) ----
    // thread owns columns u = tid*4 .. tid*4+3 for ALL 4 queries; W1 read once/block
    {
        const float4 bv4 = ((const float4*)bff1)[tid];
        float acc[4][4];
#pragma unroll
        for (int q = 0; q < 4; q++) {
            acc[q][0] = bv4.x; acc[q][1] = bv4.y; acc[q][2] = bv4.z; acc[q][3] = bv4.w;
        }
        const float4* w1v = (const float4*)W1;   // elem (k*1024 + tid*4)/4 = k*256 + tid
        for (int k4 = 0; k4 < DM; k4 += 4) {
            float4 xq[4];
#pragma unroll
            for (int q = 0; q < 4; q++) xq[q] = *(const float4*)&xs[q][k4];
#pragma unroll
            for (int dk = 0; dk < 4; dk++) {
                const float4 wv = w1v[(size_t)(k4 + dk) * 256 + tid];
#pragma unroll
                for (int q = 0; q < 4; q++) {
                    const float xk = (&xq[q].x)[dk];
                    acc[q][0] = fmaf(wv.x, xk, acc[q][0]);
                    acc[q][1] = fmaf(wv.y, xk, acc[q][1]);
                    acc[q][2] = fmaf(wv.z, xk, acc[q][2]);
                    acc[q][3] = fmaf(wv.w, xk, acc[q][3]);
                }
            }
        }
#pragma unroll
        for (int q = 0; q < 4; q++) {
            float4 h;
            h.x = fmaxf(acc[q][0], 0.f);
            h.y = fmaxf(acc[q][1], 0.f);
            h.z = fmaxf(acc[q][2], 0.f);
            h.w = fmaxf(acc[q][3], 0.f);
            *(float4*)&hid[q][tid * 4] = h;
        }
    }
    __syncthreads();

    // ---- phase E2 (cooperative): y = hidden @ W2 + bff2; W2 read once/block ----
    // thread (uc = tid>>6, c = tid&63) handles u in [uc*256, uc*256+256) for col c
    {
        const int c = lane;
        const int uc = w;
        float part[4] = {0.f, 0.f, 0.f, 0.f};
        const float* w2p = W2 + (size_t)uc * 256 * DM + c;
        const int ub = uc * 256;
        for (int u4 = 0; u4 < 256; u4 += 4) {
            const float4 h0 = *(const float4*)&hid[0][ub + u4];
            const float4 h1 = *(const float4*)&hid[1][ub + u4];
            const float4 h2 = *(const float4*)&hid[2][ub + u4];
            const float4 h3 = *(const float4*)&hid[3][ub + u4];
#pragma unroll
            for (int du = 0; du < 4; du++) {
                const float wv = w2p[(size_t)(u4 + du) * DM];
                part[0] = fmaf((&h0.x)[du], wv, part[0]);
                part[1] = fmaf((&h1.x)[du], wv, part[1]);
                part[2] = fmaf((&h2.x)[du], wv, part[2]);
                part[3] = fmaf((&h3.x)[du], wv, part[3]);
            }
        }
#pragma unroll
        for (int q = 0; q < 4; q++) red[uc][q][c] = part[q];
    }
    __syncthreads();

    // ---- final: reduce 4 partials, +bff2, residual, LN2, store (wave w = query w) ----
    {
        const float y = red[0][w][lane] + red[1][w][lane] + red[2][w][lane] + red[3][w][lane]
                        + bff2[lane];
        const float xpre = xs[w][lane] + y;
        float s = xpre, s2 = xpre * xpre;
#pragma unroll
        for (int o = 32; o >= 1; o >>= 1) {
            s += __shfl_xor(s, o, 64);
            s2 += __shfl_xor(s2, o, 64);
        }
        const float mean = s * (1.f / 64.f);
        const float var = s2 * (1.f / 64.f) - mean * mean;
        const float xn = (xpre - mean) * rsqrtf(var + 1e-5f);
        out[(size_t)qi * DM + lane] = xn * g2[lane] + b2[lane];
    }
}

extern "C" void kernel_launch(void* const* d_in, const int* in_sizes, int n_in,
                              void* d_out, int out_size, void* d_ws, size_t ws_size,
                              hipStream_t stream) {
    // Weight base auto-detect: int arrays present -> weights start at 6, else 4.
    const int B0 = (in_sizes[4] >= 4096) ? 4 : 6;
    const float* q_feat = (const float*)d_in[0];
    const float* dvf    = (const float*)d_in[1];
    const float* refp   = (const float*)d_in[2];
    const float* q_pos  = (const float*)d_in[3];
    const float* Wv   = (const float*)d_in[B0 + 0];
    const float* bv   = (const float*)d_in[B0 + 1];
    const float* Wo   = (const float*)d_in[B0 + 2];
    const float* bo   = (const float*)d_in[B0 + 3];
    const float* Wa   = (const float*)d_in[B0 + 4];
    const float* ba   = (const float*)d_in[B0 + 5];
    const float* Wout = (const float*)d_in[B0 + 6];
    const float* bout = (const float*)d_in[B0 + 7];
    const float* g1   = (const float*)d_in[B0 + 8];
    const float* b1   = (const float*)d_in[B0 + 9];
    const float* W1   = (const float*)d_in[B0 + 10];
    const float* bff1 = (const float*)d_in[B0 + 11];
    const float* W2   = (const float*)d_in[B0 + 12];
    const float* bff2 = (const float*)d_in[B0 + 13];
    const float* g2   = (const float*)d_in[B0 + 14];
    const float* b2   = (const float*)d_in[B0 + 15];
    float* out = (float*)d_out;

    const size_t val_elems = (size_t)LIN * DM;
    __hip_bfloat16* val0 = (__hip_bfloat16*)d_ws;
    const bool dbuf = ws_size >= 2 * val_elems * sizeof(__hip_bfloat16);
    __hip_bfloat16* val1 = dbuf ? val0 + val_elems : val0;

    if (dbuf) {
        val_proj_kernel<<<(LIN + 3) / 4, 256, 0, stream>>>(dvf, Wv, bv, val0);
        val_proj_kernel<<<(LIN + 3) / 4, 256, 0, stream>>>(dvf + val_elems, Wv, bv, val1);
        for (int b = 0; b < NB; b++) {
            fused_kernel<<<NQ / 4, 256, 0, stream>>>(
                q_feat + (size_t)b * NQ * DM, refp + (size_t)b * NQ * 2,
                q_pos + (size_t)b * NQ * DM,
                Wo, bo, Wa, ba, Wout, bout, g1, b1, W1, bff1, W2, bff2, g2, b2,
                b == 0 ? val0 : val1, out + (size_t)b * NQ * DM);
        }
    } else {
        for (int b = 0; b < NB; b++) {
            val_proj_kernel<<<(LIN + 3) / 4, 256, 0, stream>>>(
                dvf + (size_t)b * val_elems, Wv, bv, val0);
            fused_kernel<<<NQ / 4, 256, 0, stream>>>(
                q_feat + (size_t)b * NQ * DM, refp + (size_t)b * NQ * 2,
                q_pos + (size_t)b * NQ * DM,
                Wo, bo, Wa, ba, Wout, bout, g1, b1, W1, bff1, W2, bff2, g2, b2,
                val0, out + (size_t)b * NQ * DM);
        }
    }
}

// Round 7
// 450.506 us; speedup vs baseline: 3.6472x; 1.4811x over previous
//
#include <hip/hip_runtime.h>
#include <hip/hip_bf16.h>

#define NB 2
#define NQ 20000
#define DM 64
#define NH 8
#define NL 5
#define NP 4
#define LIN 45109
#define FFN 1024

typedef __attribute__((ext_vector_type(8))) short short8;
typedef __attribute__((ext_vector_type(4))) float f32x4;

// ---- kernel 1: val[row,c] = (dvf_b[row,:] @ Wv + bv)[c], one batch, bf16 out ----
__global__ void val_proj_kernel(const float* __restrict__ dvf_b,
                                const float* __restrict__ Wv,
                                const float* __restrict__ bv,
                                __hip_bfloat16* __restrict__ val) {
    const int lane = threadIdx.x & 63;
    const int row = blockIdx.x * 4 + (threadIdx.x >> 6);
    if (row >= LIN) return;
    float mine = dvf_b[(size_t)row * DM + lane];
    float acc = bv[lane];
#pragma unroll 8
    for (int k = 0; k < DM; k++) {
        float vk = __shfl(mine, k, 64);
        acc = fmaf(vk, Wv[k * DM + lane], acc);
    }
    val[(size_t)row * DM + lane] = __float2bfloat16(acc);
}

// ---- kernel 2: pack W1/W2 to bf16 MFMA B-fragment order ----
// B-frag 16x16x32: lane holds B[k=(lane>>4)*8+j][n=lane&15], j=0..7.
__global__ void pack_kernel(const float* __restrict__ W1, const float* __restrict__ W2,
                            __hip_bfloat16* __restrict__ W1p, __hip_bfloat16* __restrict__ W2p) {
    const int t = blockIdx.x * 256 + threadIdx.x;
    const int lane = t & 63;
    const int m = lane & 15, qd = lane >> 4;
    const int seg = t >> 6;
    if (seg < 128) {                  // W1 (64x1024): 64 ntiles x 2 kchunks
        const int nt = seg >> 1, kc = seg & 1;
        const int n = nt * 16 + m, kb = kc * 32 + qd * 8;
        __hip_bfloat16* dst = W1p + ((size_t)seg * 64 + lane) * 8;
#pragma unroll
        for (int j = 0; j < 8; j++) dst[j] = __float2bfloat16(W1[(size_t)(kb + j) * FFN + n]);
    } else {                          // W2 (1024x64): 4 ntiles x 32 kchunks
        const int sl = seg - 128;
        const int nt = sl >> 5, kc = sl & 31;
        const int n = nt * 16 + m, kb = kc * 32 + qd * 8;
        __hip_bfloat16* dst = W2p + ((size_t)sl * 64 + lane) * 8;
#pragma unroll
        for (int j = 0; j < 8; j++) dst[j] = __float2bfloat16(W2[(size_t)(kb + j) * DM + n]);
    }
}

// ---- kernel 3: attn (R5's passing f32 code, phases A-D + LN1), writes x1 ----
__global__ void __launch_bounds__(256)
attn_kernel(const float* __restrict__ q_feat,
            const float* __restrict__ ref_pts,
            const float* __restrict__ q_pos,
            const float* __restrict__ Wo, const float* __restrict__ bo,
            const float* __restrict__ Wa, const float* __restrict__ ba,
            const float* __restrict__ Wout, const float* __restrict__ bout,
            const float* __restrict__ g1, const float* __restrict__ b1,
            const __hip_bfloat16* __restrict__ val,
            float* __restrict__ xout) {
    __shared__ __align__(16) float qs[4][DM];
    __shared__ __align__(16) float offs[4][NH * NL * NP * 2];   // 320
    __shared__ __align__(16) float aws[4][NH * NL * NP];        // 160
    __shared__ __align__(16) float outv[4][DM];

    const int tid = threadIdx.x;
    const int lane = tid & 63;
    const int w = tid >> 6;
    const int qi = blockIdx.x * 4 + w;

    const int sz[NL]  = {184, 92, 46, 23, 12};
    const int lsi[NL] = {0, 33856, 42320, 44436, 44965};

    // ---- phase A ----
    const float qf = q_feat[(size_t)qi * DM + lane];
    const float qp = q_pos[(size_t)qi * DM + lane];
    qs[w][lane] = qf + qp;
    const float refx = ref_pts[(size_t)qi * 2 + 0];
    const float refy = ref_pts[(size_t)qi * 2 + 1];
    __syncthreads();

    // ---- phase B (cooperative f32): 480 cols, 2 per thread ----
    {
        const int v1 = tid + 256;
        const float* base1;
        int stride1;
        bool act1 = true;
        bool is_off1 = true;
        if (v1 < 320) { base1 = Wo + v1; stride1 = 320; }
        else if (v1 < 480) { base1 = Wa + (v1 - 320); stride1 = 160; is_off1 = false; }
        else { base1 = Wo + tid; stride1 = 320; act1 = false; }

        float a0[4] = {0.f, 0.f, 0.f, 0.f};
        float a1[4] = {0.f, 0.f, 0.f, 0.f};
        for (int k4 = 0; k4 < DM; k4 += 4) {
            const float4 q0 = *(const float4*)&qs[0][k4];
            const float4 q1 = *(const float4*)&qs[1][k4];
            const float4 q2 = *(const float4*)&qs[2][k4];
            const float4 q3 = *(const float4*)&qs[3][k4];
#pragma unroll
            for (int dk = 0; dk < 4; dk++) {
                const int k = k4 + dk;
                const float w0 = Wo[k * 320 + tid];
                const float w1 = base1[k * stride1];
                const float e0 = (&q0.x)[dk], e1 = (&q1.x)[dk];
                const float e2 = (&q2.x)[dk], e3 = (&q3.x)[dk];
                a0[0] = fmaf(e0, w0, a0[0]); a1[0] = fmaf(e0, w1, a1[0]);
                a0[1] = fmaf(e1, w0, a0[1]); a1[1] = fmaf(e1, w1, a1[1]);
                a0[2] = fmaf(e2, w0, a0[2]); a1[2] = fmaf(e2, w1, a1[2]);
                a0[3] = fmaf(e3, w0, a0[3]); a1[3] = fmaf(e3, w1, a1[3]);
            }
        }
        const float bo0 = bo[tid];
#pragma unroll
        for (int q = 0; q < 4; q++) offs[q][tid] = a0[q] + bo0;
        if (act1) {
            if (is_off1) {
                const float bb = bo[v1];
#pragma unroll
                for (int q = 0; q < 4; q++) offs[q][v1] = a1[q] + bb;
            } else {
                const float bb = ba[v1 - 320];
#pragma unroll
                for (int q = 0; q < 4; q++) aws[q][v1 - 320] = a1[q] + bb;
            }
        }
    }
    __syncthreads();

    // ---- softmax per head over 20 ----
    if (lane < NH) {
        float* p = &aws[w][lane * (NL * NP)];
        float m = p[0];
        for (int j = 1; j < NL * NP; j++) m = fmaxf(m, p[j]);
        float s = 0.f;
        for (int j = 0; j < NL * NP; j++) { float e = expf(p[j] - m); p[j] = e; s += e; }
        float inv = 1.f / s;
        for (int j = 0; j < NL * NP; j++) p[j] *= inv;
    }
    __syncthreads();

    // ---- phase C: bilinear sampling; lane = h*8 + d ----
    {
        const int h = lane >> 3;
        const __hip_bfloat16* vbase = val + lane;
        float acc = 0.f;
#pragma unroll
        for (int l = 0; l < NL; l++) {
            const int Wl = sz[l];
            const float Wf = (float)Wl;
            const int st = lsi[l];
#pragma unroll
            for (int p = 0; p < NP; p++) {
                const int c = ((h * NL + l) * NP + p) * 2;
                const float ox = offs[w][c], oy = offs[w][c + 1];
                const float fx = (refx + ox / Wf) * Wf - 0.5f;
                const float fy = (refy + oy / Wf) * Wf - 0.5f;
                const float x0f = floorf(fx), y0f = floorf(fy);
                const float wx = fx - x0f, wy = fy - y0f;
                const int x0 = (int)x0f, y0 = (int)y0f;
                const float aV = aws[w][h * (NL * NP) + l * NP + p];
                float s = 0.f;
                if (x0 >= 0 && x0 < Wl && y0 >= 0 && y0 < Wl)
                    s = fmaf(__bfloat162float(vbase[(size_t)(st + y0 * Wl + x0) * DM]), (1.f - wx) * (1.f - wy), s);
                if (x0 + 1 >= 0 && x0 + 1 < Wl && y0 >= 0 && y0 < Wl)
                    s = fmaf(__bfloat162float(vbase[(size_t)(st + y0 * Wl + x0 + 1) * DM]), wx * (1.f - wy), s);
                if (x0 >= 0 && x0 < Wl && y0 + 1 >= 0 && y0 + 1 < Wl)
                    s = fmaf(__bfloat162float(vbase[(size_t)(st + (y0 + 1) * Wl + x0) * DM]), (1.f - wx) * wy, s);
                if (x0 + 1 >= 0 && x0 + 1 < Wl && y0 + 1 >= 0 && y0 + 1 < Wl)
                    s = fmaf(__bfloat162float(vbase[(size_t)(st + (y0 + 1) * Wl + x0 + 1) * DM]), wx * wy, s);
                acc = fmaf(aV, s, acc);
            }
        }
        outv[w][lane] = acc;
    }
    __syncthreads();

    // ---- phase D: attn @ Wout + bout; residual; LN1; store x1 ----
    {
        float attn = bout[lane];
#pragma unroll 8
        for (int k = 0; k < DM; k++)
            attn = fmaf(outv[w][k], Wout[k * DM + lane], attn);
        const float xpre = qf + attn;
        float s = xpre, s2 = xpre * xpre;
#pragma unroll
        for (int o = 32; o >= 1; o >>= 1) {
            s += __shfl_xor(s, o, 64);
            s2 += __shfl_xor(s2, o, 64);
        }
        const float mean = s * (1.f / 64.f);
        const float var = s2 * (1.f / 64.f) - mean * mean;
        const float xn = (xpre - mean) * rsqrtf(var + 1e-5f);
        xout[(size_t)qi * DM + lane] = xn * g1[lane] + b1[lane];
    }
}

// ---- kernel 4: FFN via MFMA, 16 queries/block; reads x1 from io, writes out to io ----
__global__ void __launch_bounds__(256)
ffn_kernel(const __hip_bfloat16* __restrict__ W1p, const float* __restrict__ bff1,
           const __hip_bfloat16* __restrict__ W2p, const float* __restrict__ bff2,
           const float* __restrict__ g2, const float* __restrict__ b2,
           float* __restrict__ io) {
    __shared__ __align__(16) __hip_bfloat16 xb[16][72];
    __shared__ __align__(16) float xs[16][64];
    __shared__ __align__(16) __hip_bfloat16 hb[16][520];
    __shared__ __align__(16) float yr[16][64];

    const int tid = threadIdx.x;
    const int lane = tid & 63;
    const int w = tid >> 6;
    const int m16 = lane & 15, qd = lane >> 4;
    const int q0 = blockIdx.x * 16;

    // ---- load x1 (block-disjoint region of io) ----
    {
        const int q = tid >> 4, i = tid & 15;
        const float4 v = *(const float4*)&io[(size_t)(q0 + q) * DM + i * 4];
        *(float4*)&xs[q][i * 4] = v;
        xb[q][i * 4 + 0] = __float2bfloat16(v.x);
        xb[q][i * 4 + 1] = __float2bfloat16(v.y);
        xb[q][i * 4 + 2] = __float2bfloat16(v.z);
        xb[q][i * 4 + 3] = __float2bfloat16(v.w);
    }
    __syncthreads();

    f32x4 yacc = {0.f, 0.f, 0.f, 0.f};
#pragma unroll
    for (int half = 0; half < 2; half++) {
        // GEMM1: hidden half = relu(x1 @ W1 + bff1)
#pragma unroll 2
        for (int ti = 0; ti < 8; ti++) {
            const int nt = half * 32 + w + ti * 4;
            f32x4 acc = {0.f, 0.f, 0.f, 0.f};
#pragma unroll
            for (int kc = 0; kc < 2; kc++) {
                const short8 a = *(const short8*)&xb[m16][kc * 32 + qd * 8];
                const short8 b = *(const short8*)(W1p + ((size_t)(nt * 2 + kc) * 64 + lane) * 8);
                acc = __builtin_amdgcn_mfma_f32_16x16x32_bf16(a, b, acc, 0, 0, 0);
            }
            const int ncol = (nt - half * 32) * 16 + m16;   // 0..511
            const float bn = bff1[nt * 16 + m16];
#pragma unroll
            for (int r = 0; r < 4; r++)
                hb[qd * 4 + r][ncol] = __float2bfloat16(fmaxf(acc[r] + bn, 0.f));
        }
        __syncthreads();
        // GEMM2 partial: wave w owns output ntile w
#pragma unroll 4
        for (int kc2 = 0; kc2 < 16; kc2++) {
            const short8 a = *(const short8*)&hb[m16][kc2 * 32 + qd * 8];
            const short8 b = *(const short8*)(W2p + ((size_t)(w * 32 + half * 16 + kc2) * 64 + lane) * 8);
            yacc = __builtin_amdgcn_mfma_f32_16x16x32_bf16(a, b, yacc, 0, 0, 0);
        }
        __syncthreads();
    }

    // ---- Y + bff2 + x1 residual ----
    {
        const int n = w * 16 + m16;
        const float bn = bff2[n];
#pragma unroll
        for (int r = 0; r < 4; r++) {
            const int mm = qd * 4 + r;
            yr[mm][n] = yacc[r] + bn + xs[mm][n];
        }
    }
    __syncthreads();

    // ---- LN2 + store ----
    {
        const int q = tid >> 4, i = tid & 15;
        const float4 v = *(const float4*)&yr[q][i * 4];
        float s = v.x + v.y + v.z + v.w;
        float s2 = v.x * v.x + v.y * v.y + v.z * v.z + v.w * v.w;
#pragma unroll
        for (int o = 8; o >= 1; o >>= 1) { s += __shfl_xor(s, o, 64); s2 += __shfl_xor(s2, o, 64); }
        const float mean = s * (1.f / 64.f);
        const float var = s2 * (1.f / 64.f) - mean * mean;
        const float rstd = rsqrtf(var + 1e-5f);
        const float4 g = *(const float4*)&g2[i * 4];
        const float4 bb = *(const float4*)&b2[i * 4];
        float4 o;
        o.x = (v.x - mean) * rstd * g.x + bb.x;
        o.y = (v.y - mean) * rstd * g.y + bb.y;
        o.z = (v.z - mean) * rstd * g.z + bb.z;
        o.w = (v.w - mean) * rstd * g.w + bb.w;
        *(float4*)&io[(size_t)(q0 + q) * DM + i * 4] = o;
    }
}

extern "C" void kernel_launch(void* const* d_in, const int* in_sizes, int n_in,
                              void* d_out, int out_size, void* d_ws, size_t ws_size,
                              hipStream_t stream) {
    const int B0 = (in_sizes[4] >= 4096) ? 4 : 6;   // int side-inputs present -> 6
    const float* q_feat = (const float*)d_in[0];
    const float* dvf    = (const float*)d_in[1];
    const float* refp   = (const float*)d_in[2];
    const float* q_pos  = (const float*)d_in[3];
    const float* Wv   = (const float*)d_in[B0 + 0];
    const float* bv   = (const float*)d_in[B0 + 1];
    const float* Wo   = (const float*)d_in[B0 + 2];
    const float* bo   = (const float*)d_in[B0 + 3];
    const float* Wa   = (const float*)d_in[B0 + 4];
    const float* ba   = (const float*)d_in[B0 + 5];
    const float* Wout = (const float*)d_in[B0 + 6];
    const float* bout = (const float*)d_in[B0 + 7];
    const float* g1   = (const float*)d_in[B0 + 8];
    const float* b1   = (const float*)d_in[B0 + 9];
    const float* W1   = (const float*)d_in[B0 + 10];
    const float* bff1 = (const float*)d_in[B0 + 11];
    const float* W2   = (const float*)d_in[B0 + 12];
    const float* bff2 = (const float*)d_in[B0 + 13];
    const float* g2   = (const float*)d_in[B0 + 14];
    const float* b2   = (const float*)d_in[B0 + 15];
    float* out = (float*)d_out;

    const size_t val_elems = (size_t)LIN * DM;
    const size_t pack_elems = (size_t)256 * 64 * 8;     // 131072 bf16
    const bool dbuf = ws_size >= (2 * val_elems + pack_elems) * sizeof(__hip_bfloat16);

    __hip_bfloat16* val0 = (__hip_bfloat16*)d_ws;
    __hip_bfloat16* val1 = dbuf ? val0 + val_elems : val0;
    __hip_bfloat16* W1p = val0 + (dbuf ? 2 * val_elems : val_elems);
    __hip_bfloat16* W2p = W1p + (size_t)128 * 64 * 8;

    pack_kernel<<<64, 256, 0, stream>>>(W1, W2, W1p, W2p);

    if (dbuf) {
        val_proj_kernel<<<(LIN + 3) / 4, 256, 0, stream>>>(dvf, Wv, bv, val0);
        val_proj_kernel<<<(LIN + 3) / 4, 256, 0, stream>>>(dvf + val_elems, Wv, bv, val1);
        for (int b = 0; b < NB; b++) {
            attn_kernel<<<NQ / 4, 256, 0, stream>>>(
                q_feat + (size_t)b * NQ * DM, refp + (size_t)b * NQ * 2,
                q_pos + (size_t)b * NQ * DM,
                Wo, bo, Wa, ba, Wout, bout, g1, b1,
                b == 0 ? val0 : val1, out + (size_t)b * NQ * DM);
        }
    } else {
        for (int b = 0; b < NB; b++) {
            val_proj_kernel<<<(LIN + 3) / 4, 256, 0, stream>>>(
                dvf + (size_t)b * val_elems, Wv, bv, val0);
            attn_kernel<<<NQ / 4, 256, 0, stream>>>(
                q_feat + (size_t)b * NQ * DM, refp + (size_t)b * NQ * 2,
                q_pos + (size_t)b * NQ * DM,
                Wo, bo, Wa, ba, Wout, bout, g1, b1,
                val0, out + (size_t)b * NQ * DM);
        }
    }
    // FFN over both batches (40000 queries), in-place on d_out
    ffn_kernel<<<(NB * NQ) / 16, 256, 0, stream>>>(W1p, bff1, W2p, bff2, g2, b2, out);
}